// Round 16
// baseline (508.618 us; speedup 1.0000x reference)
//
#include <hip/hip_runtime.h>
#include <stdint.h>
#include <stddef.h>

// ---------------- problem constants ----------------
#define NND 100000   // nodes
#define NED 200000   // edges
#define NG  128      // graphs
// D=32, D_LIN=128, F_EDGE=16, F_GRAPH=8, MP_TIMES=3, STEPS=3

#define EB 96                 // edges per k_msgf block (mi=3) -- R13-verified optimum
#define MSGF_GRID ((NED + EB - 1) / EB)
#define HID_BLOCKS (NED*32/256)      // 25000
#define LIN0_BLOCKS ((NND + 31) / 32) // 3125

typedef unsigned short us4v __attribute__((ext_vector_type(4)));
typedef short bf16x8 __attribute__((ext_vector_type(8)));
typedef float f32x4 __attribute__((ext_vector_type(4)));

__device__ __forceinline__ float bf2f(unsigned short u){
  union{unsigned u; float f;} v; v.u = ((unsigned)u)<<16; return v.f;
}
__device__ __forceinline__ unsigned short f2bf(float f){
  union{float f; unsigned u;} v; v.f = f;
  unsigned r = v.u + 0x7FFFu + ((v.u>>16)&1u);
  return (unsigned short)(r>>16);
}
__device__ __forceinline__ float sigm(float x){ return 1.f/(1.f+__expf(-x)); }
__device__ __forceinline__ float tanh_(float x){ return 2.f/(1.f+__expf(-2.f*x)) - 1.f; }

// ---------------- fallback workspace ----------------
static const size_t kNeed = 90000000ull;
static void* g_fb = nullptr;
namespace {
struct FB { FB(){ if (hipMalloc(&g_fb, kNeed) != hipSuccess) g_fb = nullptr; } };
static FB g_fb_init;
}

// ---------------- kernels ----------------

// Block-partitioned prologue (all parts independent, disjoint outputs):
//  [0,512)            : Btbl per-lane fragment order + b2tl
//  512                : starts/counts via binary search over sorted batch
//  (512,1024)         : zero agg and deg
//  [1024,1024+25000)  : H = relu(edge_attr @ nn1 + b1), bf16 (ea staged in LDS, 1x read)
//  [26024,26024+3125) : cur = relu(x @ lin0_w + lin0_b)
// deg atomics stay a SEPARATE dispatch (must order after zeroing).
__global__ __launch_bounds__(256) void k_misc(const float* __restrict__ nn2, const float* __restrict__ b2,
                                              unsigned short* __restrict__ Btbl, float* __restrict__ b2tl,
                                              const int* __restrict__ batch,
                                              int* __restrict__ starts, int* __restrict__ counts,
                                              float* __restrict__ deg, float* __restrict__ agg,
                                              const float* __restrict__ ea, const float* __restrict__ w1,
                                              const float* __restrict__ b1, unsigned short* __restrict__ H,
                                              const float* __restrict__ x, const float* __restrict__ w0,
                                              const float* __restrict__ b0, float* __restrict__ cur){
  __shared__ float swh[2048]; __shared__ float sbh[128];   // hidden
  __shared__ float sea[8][16];                             // staged edge_attr rows
  __shared__ float sw0[1024]; __shared__ float sb0[32];    // lin0
  __shared__ float sx0[8][32];
  __shared__ int s[129];
  int b = blockIdx.x;
  if (b < 512){
    int t = b*256 + threadIdx.x;       // 131072 total
    int j  = t & 7;
    int ln = (t >> 3) & 63;
    int ni = (t >> 9) & 3;
    int ks = (t >> 11) & 3;
    int wc = (t >> 13) & 1;
    int cg = t >> 14;
    int k = ks*32 + (ln >> 4)*8 + j;
    int o = wc*16 + (ln & 15);
    int d = cg*4 + ni;
    Btbl[t] = f2bf(nn2[(k << 10) + d*32 + o]);
    if (t < 1024){
      int ni2 = t & 3, r2 = (t >> 2) & 15, wc2 = (t >> 6) & 1, cg2 = t >> 7;
      int o2 = wc2*16 + r2, d2 = cg2*4 + ni2;
      b2tl[t] = b2[d2*32 + o2];
    }
  } else if (b == 512){
    int g = threadIdx.x;
    if (g < 128){
      int lo = 0, hi = NND;
      while (lo < hi){ int mid = (lo + hi) >> 1; if (batch[mid] < g) lo = mid + 1; else hi = mid; }
      s[g] = lo;
      if (g == 0) s[128] = NND;
    }
    __syncthreads();
    if (g < 128){ starts[g] = s[g]; counts[g] = s[g+1] - s[g]; }
  } else if (b < 1024){
    int idx = (b - 513)*256 + threadIdx.x;   // 511 zero-blocks
    const int stride = 511*256;
    float4 z; z.x=0.f; z.y=0.f; z.z=0.f; z.w=0.f;
    for (int i = idx; i < (NND*32)/4; i += stride) ((float4*)agg)[i] = z;
    for (int i = idx; i < NND; i += stride) deg[i] = 0.f;
  } else if (b < 1024 + HID_BLOCKS){
    int e0 = (b - 1024)*8;               // 8 edges per block
    for (int i=threadIdx.x;i<2048;i+=256) swh[i]=w1[i];
    if (threadIdx.x<128){
      sbh[threadIdx.x]=b1[threadIdx.x];
      ((float*)sea)[threadIdx.x] = ea[(size_t)e0*16 + threadIdx.x];
    }
    __syncthreads();
    int el = threadIdx.x >> 5, q = threadIdx.x & 31;
    const float* ar = sea[el];
    float c0=sbh[q*4], c1=sbh[q*4+1], c2=sbh[q*4+2], c3=sbh[q*4+3];
    #pragma unroll
    for (int k=0;k<16;k++){
      float av=ar[k]; const float* wr = &swh[k*128 + q*4];
      c0 += av*wr[0]; c1 += av*wr[1]; c2 += av*wr[2]; c3 += av*wr[3];
    }
    us4v o;
    o[0]=f2bf(fmaxf(c0,0.f)); o[1]=f2bf(fmaxf(c1,0.f));
    o[2]=f2bf(fmaxf(c2,0.f)); o[3]=f2bf(fmaxf(c3,0.f));
    *(us4v*)(H + (size_t)(e0+el)*128 + q*4) = o;
  } else {
    for (int i = threadIdx.x; i < 1024; i += 256) sw0[i] = w0[i];
    if (threadIdx.x < 32) sb0[threadIdx.x] = b0[threadIdx.x];
    __syncthreads();
    int lb = b - (1024 + HID_BLOCKS);
    int ln = threadIdx.x >> 5, j = threadIdx.x & 31;
    for (int it = 0; it < 4; ++it){
      int n = (lb*4 + it)*8 + ln;
      if (n >= NND) return;
      float xj = x[(size_t)n*32 + j];
      sx0[ln][j] = xj;
      float acc = sb0[j];
      #pragma unroll
      for (int d=0; d<32; d++) acc += sx0[ln][d]*sw0[d*32+j];
      cur[(size_t)n*32 + j] = fmaxf(acc, 0.f);
    }
  }
}

// deg[dst[e]] += 1  -- separate dispatch AFTER k_misc's zeroing (kernel boundary = order)
__global__ __launch_bounds__(256) void k_deg(const int* __restrict__ dst, float* __restrict__ deg){
  int e = blockIdx.x*256 + threadIdx.x;
  if (e < NED) atomicAdd(&deg[dst[e]], 1.f);
}

// Fused NNConv message pass, 96-edge tiles (mi=3; R13-verified optimum).
// cg loop unrolled x2 so the compiler can overlap cg+1's B-loads with cg's
// MFMA/contraction (latency hiding at fixed occupancy).
__global__ __launch_bounds__(256) void k_msgf(const unsigned short* __restrict__ Hb,
                                              const unsigned short* __restrict__ Btbl,
                                              const float* __restrict__ b2tl,
                                              const float* __restrict__ cur,
                                              const int* __restrict__ src, const int* __restrict__ dst,
                                              float* __restrict__ agg){
  __shared__ char smem[EB*256];          // sA: 96 rows x 256B; later aliased by s_o/s_dst
  char* sA = smem;
  float* s_o  = (float*)smem;            // [96][36] f32 = 13824B (after afr extraction)
  int*   s_dst = (int*)(smem + 13824);   // 96 ints
  int tid = threadIdx.x;
  int e0 = blockIdx.x * EB;
  int l = tid & 63, wv = tid >> 6;
  int wr = wv >> 1, wc = wv & 1;
  int r = l & 15, hi = l >> 4;
  const bf16x8* Bfrag = (const bf16x8*)Btbl;
  const float4* b2t4 = (const float4*)b2tl;

  // stage A: 96 rows x 256B (XOR-swizzled), 6 passes of 16 rows; clamp tail rows
  {
    int rr = tid >> 4, c16 = (tid & 15) * 16;
    #pragma unroll
    for (int pass = 0; pass < 6; ++pass){
      int row = pass*16 + rr;
      int ge = e0 + row; if (ge >= NED) ge = NED - 1;
      bf16x8 v = *(const bf16x8*)(Hb + (size_t)ge*128 + (tid&15)*8);
      *(bf16x8*)(sA + row*256 + (c16 ^ ((row&7)<<4))) = v;
    }
  }
  __syncthreads();
  // A fragments to regs: [mi][ks], row = wr*48 + mi*16 + r
  bf16x8 afr[3][4];
  #pragma unroll
  for (int mi=0; mi<3; ++mi){
    int row = wr*48 + mi*16 + r;
    #pragma unroll
    for (int ks=0; ks<4; ++ks){
      int kb = ks*64 + hi*16;
      afr[mi][ks] = *(bf16x8*)(sA + row*256 + (kb ^ ((row&7)<<4)));
    }
  }
  __syncthreads();                       // afr reads done before sA is reused

  // gather O rows (cur[src[e]]) and dst into reused sA region; clamp tail
  if (tid < EB) s_dst[tid] = dst[min(e0 + tid, NED-1)];
  #pragma unroll
  for (int pass=0; pass<3; ++pass){
    int idx = pass*256 + tid;            // 768 float4s: 96 rows x 8
    int row = idx >> 3, c4 = (idx & 7)*4;
    int sE = src[min(e0 + row, NED-1)];
    float4 v = *(const float4*)(cur + (size_t)sE*32 + c4);
    *(float4*)(s_o + row*36 + c4) = v;
  }
  __syncthreads();

  float macc[3][4] = {};                 // msg[e, o=wc*16+r]; e = wr*48+mi*16+hi*4+q

  #pragma unroll 2
  for (int cg = 0; cg < 8; ++cg){
    float4 bzv = b2t4[(cg*2 + wc)*16 + r];
    f32x4 acc[3][4];
    #pragma unroll
    for (int mi=0; mi<3; ++mi)
      #pragma unroll
      for (int ni=0; ni<4; ++ni){
        float bb = (ni==0)?bzv.x:(ni==1)?bzv.y:(ni==2)?bzv.z:bzv.w;
        f32x4 a; a[0]=bb; a[1]=bb; a[2]=bb; a[3]=bb;
        acc[mi][ni] = a;
      }
    #pragma unroll
    for (int ks=0; ks<4; ++ks){
      bf16x8 bfr[4];
      #pragma unroll
      for (int ni=0; ni<4; ++ni)
        bfr[ni] = Bfrag[(size_t)((((cg*2 + wc)*4 + ks)*4 + ni)*64) + l];
      #pragma unroll
      for (int mi=0; mi<3; ++mi)
        #pragma unroll
        for (int ni=0; ni<4; ++ni)
          acc[mi][ni] = __builtin_amdgcn_mfma_f32_16x16x32_bf16(afr[mi][ks], bfr[ni], acc[mi][ni], 0, 0, 0);
    }
    // lane-local contraction: acc[mi][ni][q] is ew[e][o*32 + cg*4+ni]
    #pragma unroll
    for (int mi=0; mi<3; ++mi)
      #pragma unroll
      for (int q=0; q<4; ++q){
        int e = wr*48 + mi*16 + hi*4 + q;
        float4 od = *(const float4*)(s_o + e*36 + cg*4);   // O[e, cg*4 .. +3], bcast
        macc[mi][q] += acc[mi][0][q]*od.x + acc[mi][1][q]*od.y
                     + acc[mi][2][q]*od.z + acc[mi][3][q]*od.w;
      }
  }
  // scatter: one atomic per (e, o), coalesced; guard tail edges
  #pragma unroll
  for (int mi=0; mi<3; ++mi)
    #pragma unroll
    for (int q=0; q<4; ++q){
      int e = wr*48 + mi*16 + hi*4 + q;
      if (e0 + e < NED)
        atomicAdd(&agg[(size_t)s_dst[e]*32 + wc*16 + r], macc[mi][q]);
    }
}

// m = relu(cur@root + agg/deg + cb); GRU(h=cur, in=m) -> cur. Zeroes agg after read.
// Node register-blocking x4 (R9-verified).
__global__ __launch_bounds__(256) void k_gru(float* __restrict__ cur, float* __restrict__ agg,
                                             const float* __restrict__ deg,
                                             const float* __restrict__ root_w, const float* __restrict__ conv_b,
                                             const float* __restrict__ wih, const float* __restrict__ whh,
                                             const float* __restrict__ bih, const float* __restrict__ bhh){
  __shared__ float s_root[1024], s_wih[3072], s_whh[3072], s_cb[32], s_bih[96], s_bhh[96];
  __shared__ float s_c[32][32], s_m[32][32];
  for (int i=threadIdx.x;i<1024;i+=256) s_root[i]=root_w[i];
  for (int i=threadIdx.x;i<3072;i+=256){ s_wih[i]=wih[i]; s_whh[i]=whh[i]; }
  if (threadIdx.x<32) s_cb[threadIdx.x]=conv_b[threadIdx.x];
  if (threadIdx.x<96){ s_bih[threadIdx.x]=bih[threadIdx.x]; s_bhh[threadIdx.x]=bhh[threadIdx.x]; }
  __syncthreads();
  int ln = threadIdx.x >> 5, j = threadIdx.x & 31;
  int base = blockIdx.x * 160;           // 625 blocks * 160 nodes = 100000 exact
  for (int g4 = 0; g4 < 5; ++g4){
    float c[4], a[4], idg[4];
    int n[4];
    #pragma unroll
    for (int t=0;t<4;++t){
      n[t] = base + (g4*4 + t)*8 + ln;
      c[t] = cur[(size_t)n[t]*32 + j];
      a[t] = agg[(size_t)n[t]*32 + j];
      agg[(size_t)n[t]*32 + j] = 0.f;    // re-zero for next k_msgf pass
      idg[t] = 1.f / fmaxf(deg[n[t]], 1.f);
      s_c[t*8+ln][j] = c[t];             // row private to this wave -> wave-ordered
    }
    float mm[4] = {};
    #pragma unroll 8
    for (int d=0; d<32; ++d){
      float w = s_root[d*32+j];
      #pragma unroll
      for (int t=0;t<4;++t) mm[t] += s_c[t*8+ln][d] * w;
    }
    float m[4];
    #pragma unroll
    for (int t=0;t<4;++t){
      m[t] = fmaxf(mm[t] + a[t]*idg[t] + s_cb[j], 0.f);
      s_m[t*8+ln][j] = m[t];
    }
    float gr[4], gz[4], gn[4], hr[4], hz[4], hh[4];
    #pragma unroll
    for (int t=0;t<4;++t){
      gr[t]=s_bih[j]; gz[t]=s_bih[32+j]; gn[t]=s_bih[64+j];
      hr[t]=s_bhh[j]; hz[t]=s_bhh[32+j]; hh[t]=s_bhh[64+j];
    }
    #pragma unroll 4
    for (int k=0;k<32;++k){
      float w0=s_wih[k*96+j], w1=s_wih[k*96+32+j], w2=s_wih[k*96+64+j];
      float v0=s_whh[k*96+j], v1=s_whh[k*96+32+j], v2=s_whh[k*96+64+j];
      #pragma unroll
      for (int t=0;t<4;++t){
        float mk=s_m[t*8+ln][k], ck=s_c[t*8+ln][k];
        gr[t]+=mk*w0; gz[t]+=mk*w1; gn[t]+=mk*w2;
        hr[t]+=ck*v0; hz[t]+=ck*v1; hh[t]+=ck*v2;
      }
    }
    #pragma unroll
    for (int t=0;t<4;++t){
      float r = sigm(gr[t]+hr[t]);
      float z = sigm(gz[t]+hz[t]);
      float nnv = tanh_(gn[t] + r*hh[t]);
      cur[(size_t)n[t]*32 + j] = (1.f-z)*nnv + z*c[t];
    }
  }
}

// Fused Set2Set (3 steps LSTM + segment-softmax attention) + final MLP.
__global__ __launch_bounds__(256) void k_s2s(const float* __restrict__ cur,
                                             const int* __restrict__ starts, const int* __restrict__ counts,
                                             const float* __restrict__ ga,
                                             const float* __restrict__ lwih, const float* __restrict__ lwhh,
                                             const float* __restrict__ lbih, const float* __restrict__ lbhh,
                                             const float* __restrict__ w1, const float* __restrict__ b1,
                                             const float* __restrict__ w2, const float* __restrict__ b2,
                                             float* __restrict__ ev, float* __restrict__ out){
  int g = blockIdx.x;
  int s0 = starts[g], cnt = counts[g];
  int tid = threadIdx.x;
  __shared__ float hs[32], cs[32], rv[32], sg[128];
  __shared__ float red[256];
  if (tid < 32){ hs[tid]=0.f; cs[tid]=0.f; rv[tid]=0.f; }
  __syncthreads();
  for (int step=0; step<3; ++step){
    if (tid < 128){
      int j = tid;
      float acc = lbih[j] + lbhh[j];
      #pragma unroll 8
      for (int k=0;k<32;k++){
        acc += hs[k]*(lwih[k*128+j] + lwhh[k*128+j]);
        acc += rv[k]*lwih[(32+k)*128+j];
      }
      sg[j] = acc;
    }
    __syncthreads();
    if (tid < 32){
      int j = tid;
      float cn = sigm(sg[32+j])*cs[j] + sigm(sg[j])*tanh_(sg[64+j]);
      cs[j] = cn;
      hs[j] = sigm(sg[96+j])*tanh_(cn);
    }
    __syncthreads();
    float lmax = -3.4e38f;
    for (int i = tid; i < cnt; i += 256){
      const float4* cp = (const float4*)(cur + (size_t)(s0+i)*32);
      float acc = 0.f;
      #pragma unroll
      for (int q=0;q<8;q++){ float4 v=cp[q]; acc += v.x*hs[q*4]+v.y*hs[q*4+1]+v.z*hs[q*4+2]+v.w*hs[q*4+3]; }
      ev[s0+i] = acc;
      lmax = fmaxf(lmax, acc);
    }
    red[tid] = lmax; __syncthreads();
    #pragma unroll
    for (int st=128; st>0; st>>=1){ if (tid<st) red[tid]=fmaxf(red[tid],red[tid+st]); __syncthreads(); }
    float mx = red[0]; __syncthreads();
    float vec[32];
    #pragma unroll
    for (int k=0;k<32;k++) vec[k]=0.f;
    float lsum = 0.f;
    for (int i = tid; i < cnt; i += 256){
      float w = __expf(ev[s0+i]-mx);
      lsum += w;
      const float4* cp = (const float4*)(cur + (size_t)(s0+i)*32);
      #pragma unroll
      for (int q=0;q<8;q++){ float4 v=cp[q]; vec[q*4]+=w*v.x; vec[q*4+1]+=w*v.y; vec[q*4+2]+=w*v.z; vec[q*4+3]+=w*v.w; }
    }
    red[tid] = lsum; __syncthreads();
    #pragma unroll
    for (int st=128; st>0; st>>=1){ if (tid<st) red[tid]+=red[tid+st]; __syncthreads(); }
    float inv = 1.f/red[0];
    if (tid < 32) rv[tid] = 0.f;
    __syncthreads();
    #pragma unroll
    for (int k=0;k<32;k++){
      float v = vec[k];
      #pragma unroll
      for (int o=32;o>0;o>>=1) v += __shfl_down(v, o, 64);
      if ((tid&63)==0) atomicAdd(&rv[k], v);
    }
    __syncthreads();
    if (tid < 32) rv[tid] *= inv;
    __syncthreads();
  }
  if (tid < 32){
    int j = tid;
    float acc = b1[j];
    #pragma unroll 8
    for (int k=0;k<32;k++) acc += hs[k]*w1[k*32+j];
    #pragma unroll 8
    for (int k=0;k<32;k++) acc += rv[k]*w1[(32+k)*32+j];
    #pragma unroll
    for (int k=0;k<8;k++)  acc += ga[g*8+k]*w1[(64+k)*32+j];
    float r = fmaxf(acc, 0.f)*w2[j];
    #pragma unroll
    for (int o=16;o>0;o>>=1) r += __shfl_down(r, o, 64);
    if (j == 0) out[g] = r + b2[0];
  }
}

// ---------------- launch ----------------
extern "C" void kernel_launch(void* const* d_in, const int* in_sizes, int n_in,
                              void* d_out, int out_size, void* d_ws, size_t ws_size,
                              hipStream_t stream){
  (void)in_sizes; (void)n_in; (void)out_size;
  const float* x         = (const float*)d_in[0];
  const float* edge_attr = (const float*)d_in[1];
  const float* graph_attr= (const float*)d_in[2];
  const int*   eidx      = (const int*)d_in[3];
  const int*   batch     = (const int*)d_in[4];
  const float* lin0_w    = (const float*)d_in[5];
  const float* lin0_b    = (const float*)d_in[6];
  const float* nn1_w     = (const float*)d_in[7];
  const float* nn1_b     = (const float*)d_in[8];
  const float* nn2_w     = (const float*)d_in[9];
  const float* nn2_b     = (const float*)d_in[10];
  const float* root_w    = (const float*)d_in[11];
  const float* conv_b    = (const float*)d_in[12];
  const float* gru_wih   = (const float*)d_in[13];
  const float* gru_whh   = (const float*)d_in[14];
  const float* gru_bih   = (const float*)d_in[15];
  const float* gru_bhh   = (const float*)d_in[16];
  const float* lstm_wih  = (const float*)d_in[17];
  const float* lstm_whh  = (const float*)d_in[18];
  const float* lstm_bih  = (const float*)d_in[19];
  const float* lstm_bhh  = (const float*)d_in[20];
  const float* lin1_w    = (const float*)d_in[21];
  const float* lin1_b    = (const float*)d_in[22];
  const float* lin2_w    = (const float*)d_in[23];
  const float* lin2_b    = (const float*)d_in[24];
  const int* src = eidx;
  const int* dst = eidx + NED;

  char* pool = (ws_size >= kNeed) ? (char*)d_ws : (char*)g_fb;
  if (!pool) pool = (char*)d_ws;   // last resort
  size_t off = 0;
  auto alloc = [&](size_t bytes)->char* {
    char* p = pool + off; off += (bytes + 511) & ~(size_t)511; return p;
  };
  unsigned short* H   = (unsigned short*)alloc((size_t)NED*128*2);   // 51.2 MB, bf16
  float* cur  = (float*)alloc((size_t)NND*32*4);
  float* agg  = (float*)alloc((size_t)NND*32*4);
  float* deg  = (float*)alloc((size_t)NND*4);
  float* ev   = (float*)alloc((size_t)NND*4);
  unsigned short* Btbl = (unsigned short*)alloc(1024*128*2);         // bf16, fragment-ordered
  float* b2tl = (float*)alloc(1024*4);
  int*   counts = (int*)alloc(512);
  int*   startsb= (int*)alloc(512);

  k_misc<<<1024 + HID_BLOCKS + LIN0_BLOCKS, 256, 0, stream>>>(
      nn2_w, nn2_b, Btbl, b2tl, batch, startsb, counts, deg, agg,
      edge_attr, nn1_w, nn1_b, H, x, lin0_w, lin0_b, cur);
  k_deg<<<(NED+255)/256, 256, 0, stream>>>(dst, deg);

  for (int it=0; it<3; ++it){
    k_msgf<<<MSGF_GRID, 256, 0, stream>>>(H, Btbl, b2tl, cur, src, dst, agg);
    k_gru<<<625, 256, 0, stream>>>(cur, agg, deg, root_w, conv_b,
                                   gru_wih, gru_whh, gru_bih, gru_bhh);
  }
  k_s2s<<<NG, 256, 0, stream>>>(cur, startsb, counts, graph_attr,
                                lstm_wih, lstm_whh, lstm_bih, lstm_bhh,
                                lin1_w, lin1_b, lin2_w, lin2_b, ev, (float*)d_out);
}

// Round 17
// 467.110 us; speedup vs baseline: 1.0889x; 1.0889x over previous
//
#include <hip/hip_runtime.h>
#include <stdint.h>
#include <stddef.h>

// ---------------- problem constants ----------------
#define NND 100000   // nodes
#define NED 200000   // edges
#define NG  128      // graphs
// D=32, D_LIN=128, F_EDGE=16, F_GRAPH=8, MP_TIMES=3, STEPS=3

#define EB 96                 // edges per k_msgf block (mi=3) -- R13-verified optimum
#define MSGF_GRID ((NED + EB - 1) / EB)
#define HID_BLOCKS (NED*32/256)      // 25000
#define LIN0_BLOCKS ((NND + 31) / 32) // 3125

typedef unsigned short us4v __attribute__((ext_vector_type(4)));
typedef short bf16x8 __attribute__((ext_vector_type(8)));
typedef float f32x4 __attribute__((ext_vector_type(4)));

__device__ __forceinline__ float bf2f(unsigned short u){
  union{unsigned u; float f;} v; v.u = ((unsigned)u)<<16; return v.f;
}
__device__ __forceinline__ unsigned short f2bf(float f){
  union{float f; unsigned u;} v; v.f = f;
  unsigned r = v.u + 0x7FFFu + ((v.u>>16)&1u);
  return (unsigned short)(r>>16);
}
__device__ __forceinline__ float sigm(float x){ return 1.f/(1.f+__expf(-x)); }
__device__ __forceinline__ float tanh_(float x){ return 2.f/(1.f+__expf(-2.f*x)) - 1.f; }

// ---------------- fallback workspace ----------------
static const size_t kNeed = 90000000ull;
static void* g_fb = nullptr;
namespace {
struct FB { FB(){ if (hipMalloc(&g_fb, kNeed) != hipSuccess) g_fb = nullptr; } };
static FB g_fb_init;
}

// ---------------- kernels ----------------

// Block-partitioned prologue (all parts independent, disjoint outputs):
//  [0,512)            : Btbl per-lane fragment order + b2tl
//  512                : starts/counts via binary search over sorted batch
//  (512,1024)         : zero agg and deg
//  [1024,1024+25000)  : H = relu(edge_attr @ nn1 + b1), bf16 (ea staged in LDS, 1x read)
//  [26024,26024+3125) : cur = relu(x @ lin0_w + lin0_b)
// deg atomics stay a SEPARATE dispatch (must order after zeroing).
__global__ __launch_bounds__(256) void k_misc(const float* __restrict__ nn2, const float* __restrict__ b2,
                                              unsigned short* __restrict__ Btbl, float* __restrict__ b2tl,
                                              const int* __restrict__ batch,
                                              int* __restrict__ starts, int* __restrict__ counts,
                                              float* __restrict__ deg, float* __restrict__ agg,
                                              const float* __restrict__ ea, const float* __restrict__ w1,
                                              const float* __restrict__ b1, unsigned short* __restrict__ H,
                                              const float* __restrict__ x, const float* __restrict__ w0,
                                              const float* __restrict__ b0, float* __restrict__ cur){
  __shared__ float swh[2048]; __shared__ float sbh[128];   // hidden
  __shared__ float sea[8][16];                             // staged edge_attr rows
  __shared__ float sw0[1024]; __shared__ float sb0[32];    // lin0
  __shared__ float sx0[8][32];
  __shared__ int s[129];
  int b = blockIdx.x;
  if (b < 512){
    int t = b*256 + threadIdx.x;       // 131072 total
    int j  = t & 7;
    int ln = (t >> 3) & 63;
    int ni = (t >> 9) & 3;
    int ks = (t >> 11) & 3;
    int wc = (t >> 13) & 1;
    int cg = t >> 14;
    int k = ks*32 + (ln >> 4)*8 + j;
    int o = wc*16 + (ln & 15);
    int d = cg*4 + ni;
    Btbl[t] = f2bf(nn2[(k << 10) + d*32 + o]);
    if (t < 1024){
      int ni2 = t & 3, r2 = (t >> 2) & 15, wc2 = (t >> 6) & 1, cg2 = t >> 7;
      int o2 = wc2*16 + r2, d2 = cg2*4 + ni2;
      b2tl[t] = b2[d2*32 + o2];
    }
  } else if (b == 512){
    int g = threadIdx.x;
    if (g < 128){
      int lo = 0, hi = NND;
      while (lo < hi){ int mid = (lo + hi) >> 1; if (batch[mid] < g) lo = mid + 1; else hi = mid; }
      s[g] = lo;
      if (g == 0) s[128] = NND;
    }
    __syncthreads();
    if (g < 128){ starts[g] = s[g]; counts[g] = s[g+1] - s[g]; }
  } else if (b < 1024){
    int idx = (b - 513)*256 + threadIdx.x;   // 511 zero-blocks
    const int stride = 511*256;
    float4 z; z.x=0.f; z.y=0.f; z.z=0.f; z.w=0.f;
    for (int i = idx; i < (NND*32)/4; i += stride) ((float4*)agg)[i] = z;
    for (int i = idx; i < NND; i += stride) deg[i] = 0.f;
  } else if (b < 1024 + HID_BLOCKS){
    int e0 = (b - 1024)*8;               // 8 edges per block
    for (int i=threadIdx.x;i<2048;i+=256) swh[i]=w1[i];
    if (threadIdx.x<128){
      sbh[threadIdx.x]=b1[threadIdx.x];
      ((float*)sea)[threadIdx.x] = ea[(size_t)e0*16 + threadIdx.x];
    }
    __syncthreads();
    int el = threadIdx.x >> 5, q = threadIdx.x & 31;
    const float* ar = sea[el];
    float c0=sbh[q*4], c1=sbh[q*4+1], c2=sbh[q*4+2], c3=sbh[q*4+3];
    #pragma unroll
    for (int k=0;k<16;k++){
      float av=ar[k]; const float* wr = &swh[k*128 + q*4];
      c0 += av*wr[0]; c1 += av*wr[1]; c2 += av*wr[2]; c3 += av*wr[3];
    }
    us4v o;
    o[0]=f2bf(fmaxf(c0,0.f)); o[1]=f2bf(fmaxf(c1,0.f));
    o[2]=f2bf(fmaxf(c2,0.f)); o[3]=f2bf(fmaxf(c3,0.f));
    *(us4v*)(H + (size_t)(e0+el)*128 + q*4) = o;
  } else {
    for (int i = threadIdx.x; i < 1024; i += 256) sw0[i] = w0[i];
    if (threadIdx.x < 32) sb0[threadIdx.x] = b0[threadIdx.x];
    __syncthreads();
    int lb = b - (1024 + HID_BLOCKS);
    int ln = threadIdx.x >> 5, j = threadIdx.x & 31;
    for (int it = 0; it < 4; ++it){
      int n = (lb*4 + it)*8 + ln;
      if (n >= NND) return;
      float xj = x[(size_t)n*32 + j];
      sx0[ln][j] = xj;
      float acc = sb0[j];
      #pragma unroll
      for (int d=0; d<32; d++) acc += sx0[ln][d]*sw0[d*32+j];
      cur[(size_t)n*32 + j] = fmaxf(acc, 0.f);
    }
  }
}

// deg[dst[e]] += 1  -- separate dispatch AFTER k_misc's zeroing (kernel boundary = order)
__global__ __launch_bounds__(256) void k_deg(const int* __restrict__ dst, float* __restrict__ deg){
  int e = blockIdx.x*256 + threadIdx.x;
  if (e < NED) atomicAdd(&deg[dst[e]], 1.f);
}

// Fused NNConv message pass, 96-edge tiles (mi=3; R13-verified optimum).
__global__ __launch_bounds__(256) void k_msgf(const unsigned short* __restrict__ Hb,
                                              const unsigned short* __restrict__ Btbl,
                                              const float* __restrict__ b2tl,
                                              const float* __restrict__ cur,
                                              const int* __restrict__ src, const int* __restrict__ dst,
                                              float* __restrict__ agg){
  __shared__ char smem[EB*256];          // sA: 96 rows x 256B; later aliased by s_o/s_dst
  char* sA = smem;
  float* s_o  = (float*)smem;            // [96][36] f32 = 13824B (after afr extraction)
  int*   s_dst = (int*)(smem + 13824);   // 96 ints
  int tid = threadIdx.x;
  int e0 = blockIdx.x * EB;
  int l = tid & 63, wv = tid >> 6;
  int wr = wv >> 1, wc = wv & 1;
  int r = l & 15, hi = l >> 4;
  const bf16x8* Bfrag = (const bf16x8*)Btbl;
  const float4* b2t4 = (const float4*)b2tl;

  // stage A: 96 rows x 256B (XOR-swizzled), 6 passes of 16 rows; clamp tail rows
  {
    int rr = tid >> 4, c16 = (tid & 15) * 16;
    #pragma unroll
    for (int pass = 0; pass < 6; ++pass){
      int row = pass*16 + rr;
      int ge = e0 + row; if (ge >= NED) ge = NED - 1;
      bf16x8 v = *(const bf16x8*)(Hb + (size_t)ge*128 + (tid&15)*8);
      *(bf16x8*)(sA + row*256 + (c16 ^ ((row&7)<<4))) = v;
    }
  }
  __syncthreads();
  // A fragments to regs: [mi][ks], row = wr*48 + mi*16 + r
  bf16x8 afr[3][4];
  #pragma unroll
  for (int mi=0; mi<3; ++mi){
    int row = wr*48 + mi*16 + r;
    #pragma unroll
    for (int ks=0; ks<4; ++ks){
      int kb = ks*64 + hi*16;
      afr[mi][ks] = *(bf16x8*)(sA + row*256 + (kb ^ ((row&7)<<4)));
    }
  }
  __syncthreads();                       // afr reads done before sA is reused

  // gather O rows (cur[src[e]]) and dst into reused sA region; clamp tail
  if (tid < EB) s_dst[tid] = dst[min(e0 + tid, NED-1)];
  #pragma unroll
  for (int pass=0; pass<3; ++pass){
    int idx = pass*256 + tid;            // 768 float4s: 96 rows x 8
    int row = idx >> 3, c4 = (idx & 7)*4;
    int sE = src[min(e0 + row, NED-1)];
    float4 v = *(const float4*)(cur + (size_t)sE*32 + c4);
    *(float4*)(s_o + row*36 + c4) = v;
  }
  __syncthreads();

  float macc[3][4] = {};                 // msg[e, o=wc*16+r]; e = wr*48+mi*16+hi*4+q

  for (int cg = 0; cg < 8; ++cg){
    float4 bzv = b2t4[(cg*2 + wc)*16 + r];
    f32x4 acc[3][4];
    #pragma unroll
    for (int mi=0; mi<3; ++mi)
      #pragma unroll
      for (int ni=0; ni<4; ++ni){
        float bb = (ni==0)?bzv.x:(ni==1)?bzv.y:(ni==2)?bzv.z:bzv.w;
        f32x4 a; a[0]=bb; a[1]=bb; a[2]=bb; a[3]=bb;
        acc[mi][ni] = a;
      }
    #pragma unroll
    for (int ks=0; ks<4; ++ks){
      bf16x8 bfr[4];
      #pragma unroll
      for (int ni=0; ni<4; ++ni)
        bfr[ni] = Bfrag[(size_t)((((cg*2 + wc)*4 + ks)*4 + ni)*64) + l];
      #pragma unroll
      for (int mi=0; mi<3; ++mi)
        #pragma unroll
        for (int ni=0; ni<4; ++ni)
          acc[mi][ni] = __builtin_amdgcn_mfma_f32_16x16x32_bf16(afr[mi][ks], bfr[ni], acc[mi][ni], 0, 0, 0);
    }
    // lane-local contraction: acc[mi][ni][q] is ew[e][o*32 + cg*4+ni]
    #pragma unroll
    for (int mi=0; mi<3; ++mi)
      #pragma unroll
      for (int q=0; q<4; ++q){
        int e = wr*48 + mi*16 + hi*4 + q;
        float4 od = *(const float4*)(s_o + e*36 + cg*4);   // O[e, cg*4 .. +3], bcast
        macc[mi][q] += acc[mi][0][q]*od.x + acc[mi][1][q]*od.y
                     + acc[mi][2][q]*od.z + acc[mi][3][q]*od.w;
      }
  }
  // scatter: one atomic per (e, o), coalesced; guard tail edges
  #pragma unroll
  for (int mi=0; mi<3; ++mi)
    #pragma unroll
    for (int q=0; q<4; ++q){
      int e = wr*48 + mi*16 + hi*4 + q;
      if (e0 + e < NED)
        atomicAdd(&agg[(size_t)s_dst[e]*32 + wc*16 + r], macc[mi][q]);
    }
}

// m = relu(cur@root + agg/deg + cb); GRU(h=cur, in=m) -> cur. Zeroes agg after read.
// Node register-blocking x4 (R9-verified).
__global__ __launch_bounds__(256) void k_gru(float* __restrict__ cur, float* __restrict__ agg,
                                             const float* __restrict__ deg,
                                             const float* __restrict__ root_w, const float* __restrict__ conv_b,
                                             const float* __restrict__ wih, const float* __restrict__ whh,
                                             const float* __restrict__ bih, const float* __restrict__ bhh){
  __shared__ float s_root[1024], s_wih[3072], s_whh[3072], s_cb[32], s_bih[96], s_bhh[96];
  __shared__ float s_c[32][32], s_m[32][32];
  for (int i=threadIdx.x;i<1024;i+=256) s_root[i]=root_w[i];
  for (int i=threadIdx.x;i<3072;i+=256){ s_wih[i]=wih[i]; s_whh[i]=whh[i]; }
  if (threadIdx.x<32) s_cb[threadIdx.x]=conv_b[threadIdx.x];
  if (threadIdx.x<96){ s_bih[threadIdx.x]=bih[threadIdx.x]; s_bhh[threadIdx.x]=bhh[threadIdx.x]; }
  __syncthreads();
  int ln = threadIdx.x >> 5, j = threadIdx.x & 31;
  int base = blockIdx.x * 160;           // 625 blocks * 160 nodes = 100000 exact
  for (int g4 = 0; g4 < 5; ++g4){
    float c[4], a[4], idg[4];
    int n[4];
    #pragma unroll
    for (int t=0;t<4;++t){
      n[t] = base + (g4*4 + t)*8 + ln;
      c[t] = cur[(size_t)n[t]*32 + j];
      a[t] = agg[(size_t)n[t]*32 + j];
      agg[(size_t)n[t]*32 + j] = 0.f;    // re-zero for next k_msgf pass
      idg[t] = 1.f / fmaxf(deg[n[t]], 1.f);
      s_c[t*8+ln][j] = c[t];             // row private to this wave -> wave-ordered
    }
    float mm[4] = {};
    #pragma unroll 8
    for (int d=0; d<32; ++d){
      float w = s_root[d*32+j];
      #pragma unroll
      for (int t=0;t<4;++t) mm[t] += s_c[t*8+ln][d] * w;
    }
    float m[4];
    #pragma unroll
    for (int t=0;t<4;++t){
      m[t] = fmaxf(mm[t] + a[t]*idg[t] + s_cb[j], 0.f);
      s_m[t*8+ln][j] = m[t];
    }
    float gr[4], gz[4], gn[4], hr[4], hz[4], hh[4];
    #pragma unroll
    for (int t=0;t<4;++t){
      gr[t]=s_bih[j]; gz[t]=s_bih[32+j]; gn[t]=s_bih[64+j];
      hr[t]=s_bhh[j]; hz[t]=s_bhh[32+j]; hh[t]=s_bhh[64+j];
    }
    #pragma unroll 4
    for (int k=0;k<32;++k){
      float w0=s_wih[k*96+j], w1=s_wih[k*96+32+j], w2=s_wih[k*96+64+j];
      float v0=s_whh[k*96+j], v1=s_whh[k*96+32+j], v2=s_whh[k*96+64+j];
      #pragma unroll
      for (int t=0;t<4;++t){
        float mk=s_m[t*8+ln][k], ck=s_c[t*8+ln][k];
        gr[t]+=mk*w0; gz[t]+=mk*w1; gn[t]+=mk*w2;
        hr[t]+=ck*v0; hz[t]+=ck*v1; hh[t]+=ck*v2;
      }
    }
    #pragma unroll
    for (int t=0;t<4;++t){
      float r = sigm(gr[t]+hr[t]);
      float z = sigm(gz[t]+hz[t]);
      float nnv = tanh_(gn[t] + r*hh[t]);
      cur[(size_t)n[t]*32 + j] = (1.f-z)*nnv + z*c[t];
    }
  }
}

// Fused Set2Set (3 steps LSTM + segment-softmax attention) + final MLP.
__global__ __launch_bounds__(256) void k_s2s(const float* __restrict__ cur,
                                             const int* __restrict__ starts, const int* __restrict__ counts,
                                             const float* __restrict__ ga,
                                             const float* __restrict__ lwih, const float* __restrict__ lwhh,
                                             const float* __restrict__ lbih, const float* __restrict__ lbhh,
                                             const float* __restrict__ w1, const float* __restrict__ b1,
                                             const float* __restrict__ w2, const float* __restrict__ b2,
                                             float* __restrict__ ev, float* __restrict__ out){
  int g = blockIdx.x;
  int s0 = starts[g], cnt = counts[g];
  int tid = threadIdx.x;
  __shared__ float hs[32], cs[32], rv[32], sg[128];
  __shared__ float red[256];
  if (tid < 32){ hs[tid]=0.f; cs[tid]=0.f; rv[tid]=0.f; }
  __syncthreads();
  for (int step=0; step<3; ++step){
    if (tid < 128){
      int j = tid;
      float acc = lbih[j] + lbhh[j];
      #pragma unroll 8
      for (int k=0;k<32;k++){
        acc += hs[k]*(lwih[k*128+j] + lwhh[k*128+j]);
        acc += rv[k]*lwih[(32+k)*128+j];
      }
      sg[j] = acc;
    }
    __syncthreads();
    if (tid < 32){
      int j = tid;
      float cn = sigm(sg[32+j])*cs[j] + sigm(sg[j])*tanh_(sg[64+j]);
      cs[j] = cn;
      hs[j] = sigm(sg[96+j])*tanh_(cn);
    }
    __syncthreads();
    float lmax = -3.4e38f;
    for (int i = tid; i < cnt; i += 256){
      const float4* cp = (const float4*)(cur + (size_t)(s0+i)*32);
      float acc = 0.f;
      #pragma unroll
      for (int q=0;q<8;q++){ float4 v=cp[q]; acc += v.x*hs[q*4]+v.y*hs[q*4+1]+v.z*hs[q*4+2]+v.w*hs[q*4+3]; }
      ev[s0+i] = acc;
      lmax = fmaxf(lmax, acc);
    }
    red[tid] = lmax; __syncthreads();
    #pragma unroll
    for (int st=128; st>0; st>>=1){ if (tid<st) red[tid]=fmaxf(red[tid],red[tid+st]); __syncthreads(); }
    float mx = red[0]; __syncthreads();
    float vec[32];
    #pragma unroll
    for (int k=0;k<32;k++) vec[k]=0.f;
    float lsum = 0.f;
    for (int i = tid; i < cnt; i += 256){
      float w = __expf(ev[s0+i]-mx);
      lsum += w;
      const float4* cp = (const float4*)(cur + (size_t)(s0+i)*32);
      #pragma unroll
      for (int q=0;q<8;q++){ float4 v=cp[q]; vec[q*4]+=w*v.x; vec[q*4+1]+=w*v.y; vec[q*4+2]+=w*v.z; vec[q*4+3]+=w*v.w; }
    }
    red[tid] = lsum; __syncthreads();
    #pragma unroll
    for (int st=128; st>0; st>>=1){ if (tid<st) red[tid]+=red[tid+st]; __syncthreads(); }
    float inv = 1.f/red[0];
    if (tid < 32) rv[tid] = 0.f;
    __syncthreads();
    #pragma unroll
    for (int k=0;k<32;k++){
      float v = vec[k];
      #pragma unroll
      for (int o=32;o>0;o>>=1) v += __shfl_down(v, o, 64);
      if ((tid&63)==0) atomicAdd(&rv[k], v);
    }
    __syncthreads();
    if (tid < 32) rv[tid] *= inv;
    __syncthreads();
  }
  if (tid < 32){
    int j = tid;
    float acc = b1[j];
    #pragma unroll 8
    for (int k=0;k<32;k++) acc += hs[k]*w1[k*32+j];
    #pragma unroll 8
    for (int k=0;k<32;k++) acc += rv[k]*w1[(32+k)*32+j];
    #pragma unroll
    for (int k=0;k<8;k++)  acc += ga[g*8+k]*w1[(64+k)*32+j];
    float r = fmaxf(acc, 0.f)*w2[j];
    #pragma unroll
    for (int o=16;o>0;o>>=1) r += __shfl_down(r, o, 64);
    if (j == 0) out[g] = r + b2[0];
  }
}

// ---------------- launch ----------------
extern "C" void kernel_launch(void* const* d_in, const int* in_sizes, int n_in,
                              void* d_out, int out_size, void* d_ws, size_t ws_size,
                              hipStream_t stream){
  (void)in_sizes; (void)n_in; (void)out_size;
  const float* x         = (const float*)d_in[0];
  const float* edge_attr = (const float*)d_in[1];
  const float* graph_attr= (const float*)d_in[2];
  const int*   eidx      = (const int*)d_in[3];
  const int*   batch     = (const int*)d_in[4];
  const float* lin0_w    = (const float*)d_in[5];
  const float* lin0_b    = (const float*)d_in[6];
  const float* nn1_w     = (const float*)d_in[7];
  const float* nn1_b     = (const float*)d_in[8];
  const float* nn2_w     = (const float*)d_in[9];
  const float* nn2_b     = (const float*)d_in[10];
  const float* root_w    = (const float*)d_in[11];
  const float* conv_b    = (const float*)d_in[12];
  const float* gru_wih   = (const float*)d_in[13];
  const float* gru_whh   = (const float*)d_in[14];
  const float* gru_bih   = (const float*)d_in[15];
  const float* gru_bhh   = (const float*)d_in[16];
  const float* lstm_wih  = (const float*)d_in[17];
  const float* lstm_whh  = (const float*)d_in[18];
  const float* lstm_bih  = (const float*)d_in[19];
  const float* lstm_bhh  = (const float*)d_in[20];
  const float* lin1_w    = (const float*)d_in[21];
  const float* lin1_b    = (const float*)d_in[22];
  const float* lin2_w    = (const float*)d_in[23];
  const float* lin2_b    = (const float*)d_in[24];
  const int* src = eidx;
  const int* dst = eidx + NED;

  char* pool = (ws_size >= kNeed) ? (char*)d_ws : (char*)g_fb;
  if (!pool) pool = (char*)d_ws;   // last resort
  size_t off = 0;
  auto alloc = [&](size_t bytes)->char* {
    char* p = pool + off; off += (bytes + 511) & ~(size_t)511; return p;
  };
  unsigned short* H   = (unsigned short*)alloc((size_t)NED*128*2);   // 51.2 MB, bf16
  float* cur  = (float*)alloc((size_t)NND*32*4);
  float* agg  = (float*)alloc((size_t)NND*32*4);
  float* deg  = (float*)alloc((size_t)NND*4);
  float* ev   = (float*)alloc((size_t)NND*4);
  unsigned short* Btbl = (unsigned short*)alloc(1024*128*2);         // bf16, fragment-ordered
  float* b2tl = (float*)alloc(1024*4);
  int*   counts = (int*)alloc(512);
  int*   startsb= (int*)alloc(512);

  k_misc<<<1024 + HID_BLOCKS + LIN0_BLOCKS, 256, 0, stream>>>(
      nn2_w, nn2_b, Btbl, b2tl, batch, startsb, counts, deg, agg,
      edge_attr, nn1_w, nn1_b, H, x, lin0_w, lin0_b, cur);
  k_deg<<<(NED+255)/256, 256, 0, stream>>>(dst, deg);

  for (int it=0; it<3; ++it){
    k_msgf<<<MSGF_GRID, 256, 0, stream>>>(H, Btbl, b2tl, cur, src, dst, agg);
    k_gru<<<625, 256, 0, stream>>>(cur, agg, deg, root_w, conv_b,
                                   gru_wih, gru_whh, gru_bih, gru_bhh);
  }
  k_s2s<<<NG, 256, 0, stream>>>(cur, startsb, counts, graph_attr,
                                lstm_wih, lstm_whh, lstm_bih, lstm_bhh,
                                lin1_w, lin1_b, lin2_w, lin2_b, ev, (float*)d_out);
}